// Round 8
// baseline (1009.124 us; speedup 1.0000x reference)
//
#include <hip/hip_runtime.h>
#include <math.h>

// clDice loss on MI355X (gfx950).  Round-8: barrier-free single-wave blocks.
// See analysis: round-7 was VALU-issue-bound at 47% duty (2 blocks/CU,
// barrier-per-row). Now each block = 1 wave owning a 256-px column strip;
// +-1 column exchange via DPP wave_shr:1/wave_shl:1 (VALU pipe, no LDS, no
// barriers). Strip halo 8 px/side absorbs wave-boundary garbage (K=4 x
// radius 2); image edges via +inf load guards and per-lane column mask
// applied with fminf. Grid 5x32x16 = 2560 independent waves. Fused
// reduction -> per-block partials (no atomics), tiny finalize kernel.

#define IMG_H 1024
#define IMG_W 1024
#define IMG_N (IMG_H * IMG_W)
#define NIMG  16
#define BH    32
#define NBANDS (IMG_H / BH)
#define NSTRIP 5
#define SOUT  240
#define K     4
#define NBLK  (NSTRIP * NBANDS * NIMG)
#define NITER (BH + 6 * K)

__device__ __forceinline__ float min3f(float a, float b, float c) { return fminf(fminf(a, b), c); }
__device__ __forceinline__ float max3f(float a, float b, float c) { return fmaxf(fmaxf(a, b), c); }
__device__ __forceinline__ float4 f4(float v) { return make_float4(v, v, v, v); }

// lane i <- lane i-1 (DPP wave_shr:1; lane 0 keeps own value)
__device__ __forceinline__ float sh_up(float v) {
    int i = __float_as_int(v);
    return __int_as_float(__builtin_amdgcn_update_dpp(i, i, 0x138, 0xF, 0xF, false));
}
// lane i <- lane i+1 (DPP wave_shl:1; lane 63 keeps own value)
__device__ __forceinline__ float sh_dn(float v) {
    int i = __float_as_int(v);
    return __int_as_float(__builtin_amdgcn_update_dpp(i, i, 0x130, 0xF, 0xF, false));
}

__device__ __forceinline__ float4 fmax4s(float4 a, float b) {
    return make_float4(fmaxf(a.x, b), fmaxf(a.y, b), fmaxf(a.z, b), fmaxf(a.w, b));
}

struct St {
    float4 hm1, hm2;    // hmin rows ri-2, ri-1
    float4 m2, m3;      // minpool rows ri-2, ri-3
    float4 q1, q2;      // hmax rows ri-4, ri-3
    float4 x1, x2, x3;  // input rows ri-1, ri-2, ri-3
    float4 xc;          // input row ri
};

__device__ __forceinline__ float4 stage_step(St& s, float rm, const float4& cmask)
{
    float lpx = sh_up(s.xc.w), rpx = sh_dn(s.xc.x);
    float4 h;
    h.x = min3f(lpx,    s.xc.x, s.xc.y);
    h.y = min3f(s.xc.x, s.xc.y, s.xc.z);
    h.z = min3f(s.xc.y, s.xc.z, s.xc.w);
    h.w = min3f(s.xc.z, s.xc.w, rpx);
    float4 cm;
    cm.x = fminf(cmask.x, rm); cm.y = fminf(cmask.y, rm);
    cm.z = fminf(cmask.z, rm); cm.w = fminf(cmask.w, rm);
    float4 m;
    m.x = fminf(min3f(s.hm1.x, s.hm2.x, h.x), cm.x);
    m.y = fminf(min3f(s.hm1.y, s.hm2.y, h.y), cm.y);
    m.z = fminf(min3f(s.hm1.z, s.hm2.z, h.z), cm.z);
    m.w = fminf(min3f(s.hm1.w, s.hm2.w, h.w), cm.w);
    float lpm = sh_up(s.m2.w), rpm = sh_dn(s.m2.x);
    float4 q;
    q.x = max3f(lpm,    s.m2.x, s.m2.y);
    q.y = max3f(s.m2.x, s.m2.y, s.m2.z);
    q.z = max3f(s.m2.y, s.m2.z, s.m2.w);
    q.w = max3f(s.m2.z, s.m2.w, rpm);
    float4 M;
    M.x = max3f(s.q1.x, s.q2.x, q.x);
    M.y = max3f(s.q1.y, s.q2.y, q.y);
    M.z = max3f(s.q1.z, s.q2.z, q.z);
    M.w = max3f(s.q1.w, s.q2.w, q.w);
    float4 e;
    e.x = fmaxf(s.x3.x - fmaxf(M.x - s.m3.x, 0.f), 0.f);
    e.y = fmaxf(s.x3.y - fmaxf(M.y - s.m3.y, 0.f), 0.f);
    e.z = fmaxf(s.x3.z - fmaxf(M.z - s.m3.z, 0.f), 0.f);
    e.w = fmaxf(s.x3.w - fmaxf(M.w - s.m3.w, 0.f), 0.f);
    s.hm1 = s.hm2; s.hm2 = h;
    s.m3  = s.m2;  s.m2  = m;
    s.q1  = s.q2;  s.q2  = q;
    s.x3  = s.x2;  s.x2  = s.x1; s.x1 = s.xc;
    return e;
}

__device__ __forceinline__ void iter_step(
    int y, int r0, int c0, bool colok, bool storelane, const float4& cmask,
    St (&st)[K], float4& xn1,
    const float* __restrict__ s, float* __restrict__ o,
    const float* __restrict__ oth, float& a1, float& a2)
{
    const float INF = __builtin_huge_valf();
    float4 xn2 = f4(INF);
    if (colok && (unsigned)(y + 2) < IMG_H)
        xn2 = *(const float4*)(s + (size_t)(y + 2) * IMG_W + c0);

    float rm3 = ((unsigned)(y - 13) < IMG_H) ? INF : -INF;
    float4 eK = stage_step(st[3], rm3, cmask);
    float rm2 = ((unsigned)(y - 9) < IMG_H) ? INF : -INF;
    float4 e2 = stage_step(st[2], rm2, cmask);
    st[3].xc = fmax4s(e2, ((unsigned)(y - 11) < IMG_H) ? -INF : INF);
    float rm1 = ((unsigned)(y - 5) < IMG_H) ? INF : -INF;
    float4 e1 = stage_step(st[1], rm1, cmask);
    st[2].xc = fmax4s(e1, ((unsigned)(y - 7) < IMG_H) ? -INF : INF);
    float rm0 = ((unsigned)(y - 1) < IMG_H) ? INF : -INF;
    float4 e0 = stage_step(st[0], rm0, cmask);
    st[1].xc = fmax4s(e0, ((unsigned)(y - 3) < IMG_H) ? -INF : INF);
    st[0].xc = xn1;
    xn1 = xn2;

    int orow = y - 15;
    if ((unsigned)(orow - r0) < (unsigned)BH && storelane) {
        *(float4*)(o + (size_t)orow * IMG_W + c0) = eK;
        if (oth) {
            float4 ov = *(const float4*)(oth + (size_t)orow * IMG_W + c0);
            a1 += eK.x * ov.x + eK.y * ov.y + eK.z * ov.z + eK.w * ov.w;
            a2 += eK.x + eK.y + eK.z + eK.w;
        }
    }
}

__global__ __launch_bounds__(64, 2) void skel(
    const float* __restrict__ src, float* __restrict__ dst,
    const float* __restrict__ other, double* __restrict__ partials)
{
    const float INF = __builtin_huge_valf();
    const int lane  = threadIdx.x;
    const int strip = blockIdx.x, band = blockIdx.y, img = blockIdx.z;
    const int r0 = band * BH;
    const int c0 = strip * SOUT - 8 + 4 * lane;
    const bool colok     = (c0 >= 0) && (c0 + 4 <= IMG_W);
    const bool storelane = (lane >= 2) && (lane <= 61) && (c0 < IMG_W);
    float4 cmask;
    cmask.x = ((unsigned)(c0 + 0) < IMG_W) ? INF : -INF;
    cmask.y = ((unsigned)(c0 + 1) < IMG_W) ? INF : -INF;
    cmask.z = ((unsigned)(c0 + 2) < IMG_W) ? INF : -INF;
    cmask.w = ((unsigned)(c0 + 3) < IMG_W) ? INF : -INF;

    const float* s = src + (size_t)img * IMG_N;
    float*       o = dst + (size_t)img * IMG_N;
    const float* oth = other ? other + (size_t)img * IMG_N : nullptr;

    St st[K];
    #pragma unroll
    for (int k = 0; k < K; ++k) {
        st[k].hm1 = st[k].hm2 = f4(INF);
        st[k].m2 = st[k].m3 = f4(-INF);
        st[k].q1 = st[k].q2 = f4(-INF);
        st[k].x1 = st[k].x2 = st[k].x3 = f4(INF);
        st[k].xc = f4(INF);
    }

    const int y0 = r0 - 2 * K;
    if (colok && (unsigned)y0 < IMG_H)
        st[0].xc = *(const float4*)(s + (size_t)y0 * IMG_W + c0);
    float4 xn1 = f4(INF);
    if (colok && (unsigned)(y0 + 1) < IMG_H)
        xn1 = *(const float4*)(s + (size_t)(y0 + 1) * IMG_W + c0);

    float a1 = 0.f, a2 = 0.f;
    for (int p = 0; p < NITER / 2; ++p) {
        iter_step(y0 + 2 * p,     r0, c0, colok, storelane, cmask, st, xn1, s, o, oth, a1, a2);
        iter_step(y0 + 2 * p + 1, r0, c0, colok, storelane, cmask, st, xn1, s, o, oth, a1, a2);
    }

    if (oth) {
        double d1 = a1, d2 = a2;
        for (int off = 32; off; off >>= 1) {
            d1 += __shfl_down(d1, off);
            d2 += __shfl_down(d2, off);
        }
        if (lane == 0) {
            int bid = (img * NBANDS + band) * NSTRIP + strip;
            partials[2 * bid]     = d1;
            partials[2 * bid + 1] = d2;
        }
    }
}

__global__ __launch_bounds__(256) void finalize(
    const double* __restrict__ pp, const double* __restrict__ pg,
    float* __restrict__ out)
{
    __shared__ double sh[4][4];
    double i1 = 0, i2 = 0, t1 = 0, t2 = 0;
    for (int i = threadIdx.x; i < NBLK; i += 256) {
        i1 += pp[2 * i]; i2 += pp[2 * i + 1];
        t1 += pg[2 * i]; t2 += pg[2 * i + 1];
    }
    for (int off = 32; off; off >>= 1) {
        i1 += __shfl_down(i1, off); i2 += __shfl_down(i2, off);
        t1 += __shfl_down(t1, off); t2 += __shfl_down(t2, off);
    }
    const int w = threadIdx.x >> 6;
    if ((threadIdx.x & 63) == 0) { sh[0][w] = i1; sh[1][w] = i2; sh[2][w] = t1; sh[3][w] = t2; }
    __syncthreads();
    if (threadIdx.x == 0) {
        double s1 = 0, s2 = 0, s3 = 0, s4 = 0;
        for (int j = 0; j < 4; ++j) { s1 += sh[0][j]; s2 += sh[1][j]; s3 += sh[2][j]; s4 += sh[3][j]; }
        double iflat = (s1 + 1.0) / (s2 + 1.0);
        double tflat = (s3 + 1.0) / (s4 + 1.0);
        out[0] = (float)(1.0 - 2.0 * (iflat * tflat) / (iflat + tflat));
    }
}

extern "C" void kernel_launch(void* const* d_in, const int* in_sizes, int n_in,
                              void* d_out, int out_size, void* d_ws, size_t ws_size,
                              hipStream_t stream)
{
    const float* pred = (const float*)d_in[0];
    const float* gt   = (const float*)d_in[1];

    float*  bufA  = (float*)d_ws;
    float*  bufB  = bufA + (size_t)NIMG * IMG_N;
    double* partP = (double*)(bufB + (size_t)NIMG * IMG_N);
    double* partG = partP + 2 * NBLK;

    dim3 grid(NSTRIP, NBANDS, NIMG);

    // ---- pred skeleton: 5 launches x 4 fused iterations = 20 ----
    skel<<<grid, 64, 0, stream>>>(pred, bufA, nullptr, nullptr);
    skel<<<grid, 64, 0, stream>>>(bufA, bufB, nullptr, nullptr);
    skel<<<grid, 64, 0, stream>>>(bufB, bufA, nullptr, nullptr);
    skel<<<grid, 64, 0, stream>>>(bufA, bufB, nullptr, nullptr);
    skel<<<grid, 64, 0, stream>>>(bufB, bufA, gt, partP);      // + iflat partials

    // ---- gt skeleton: 5 launches ----
    skel<<<grid, 64, 0, stream>>>(gt,   bufA, nullptr, nullptr);
    skel<<<grid, 64, 0, stream>>>(bufA, bufB, nullptr, nullptr);
    skel<<<grid, 64, 0, stream>>>(bufB, bufA, nullptr, nullptr);
    skel<<<grid, 64, 0, stream>>>(bufA, bufB, nullptr, nullptr);
    skel<<<grid, 64, 0, stream>>>(bufB, bufA, pred, partG);    // + tflat partials

    finalize<<<1, 256, 0, stream>>>(partP, partG, (float*)d_out);
}

// Round 9
// 745.417 us; speedup vs baseline: 1.3538x; 1.3538x over previous
//
#include <hip/hip_runtime.h>
#include <math.h>

// clDice loss on MI355X (gfx950).
// soft_skeletonize = 20 iterations of:
//   m = minpool3(x); contour = relu(maxpool3(m) - m); x = relu(x - contour)
// Round-9: round-7's proven row-streaming K=4 pipeline (LDS edge exchange,
// 1 barrier/row-iter), with two structural fixes for the measured ~50%
// VALU-duty cap (one ~1000-cyc unhidden memory stall per row-iter at only
// 2 blocks/CU):
//  1) both tensors in one grid (z=32) -> 1024 blocks = 4 blocks/CU
//     = 16 waves/CU co-residency, same halo fraction; 5 launches total.
//  2) bf16 intermediates (fp32 compute, RNE store): halves ping-pong
//     traffic AND fits 2x32-image buffers in the proven ws budget
//     (2 x 67,108,864 B = 134,217,728 <= 134,217,984 proven safe).
// Last launch writes no skeleton - fused reduction only; per-block partials
// (no atomics) land in the then-dead A region; tiny finalize emits the loss.

#define IMG_H 1024
#define IMG_W 1024
#define IMG_N (IMG_H * IMG_W)
#define NIMG  16
#define NZ    32                    // 16 pred + 16 gt images
#define BH    32                    // output rows per band
#define NBANDS (IMG_H / BH)         // 32
#define K     4                     // fused skeleton iterations per launch
#define EW    258                   // 256 lanes + 2 guard slots
#define NBLK  (NZ * NBANDS)         // 1024 blocks per launch
#define ITER_PAIRS ((BH + 6 * K) / 2)   // 28 pairs = 56 row-iterations

__device__ __forceinline__ float min3f(float a, float b, float c) { return fminf(fminf(a, b), c); }
__device__ __forceinline__ float max3f(float a, float b, float c) { return fmaxf(fmaxf(a, b), c); }
__device__ __forceinline__ float4 f4(float v) { return make_float4(v, v, v, v); }

// ---- bf16 <-> fp32 helpers (RNE store; +-inf round-trips exactly) ----
__device__ __forceinline__ float bf2f(unsigned short u) {
    return __uint_as_float((unsigned)u << 16);
}
__device__ __forceinline__ unsigned short f2bf(float f) {
    unsigned b = __float_as_uint(f);
    return (unsigned short)((b + 0x7FFFu + ((b >> 16) & 1u)) >> 16);
}

struct St {
    float4 hm1, hm2;    // hmin rows ri-2, ri-1
    float4 m2, m3;      // minpool rows ri-2, ri-3
    float4 q1, q2;      // hmax rows ri-4, ri-3
    float4 x1, x2, x3;  // input rows ri-1, ri-2, ri-3
    float4 xc;          // input row ri
};

// One pipeline stage at input row ri. Returns output row ri-3.
// lp = left neighbor {x.w, m.w}; rp = right neighbor {x.x, m.x}.
template<int BUF>
__device__ __forceinline__ float4 stage_step(
    St& s, int ri, int t,
    const float2 (&eL)[2][EW], const float2 (&eR)[2][EW])
{
    const float INF = __builtin_huge_valf();
    float2 lp = eR[BUF][t];          // left neighbor's edges (guard at t=0)
    float2 rp = eL[BUF][t + 2];      // right neighbor's edges (guard at 257)
    float4 h;
    h.x = min3f(lp.x,   s.xc.x, s.xc.y);
    h.y = min3f(s.xc.x, s.xc.y, s.xc.z);
    h.z = min3f(s.xc.y, s.xc.z, s.xc.w);
    h.w = min3f(s.xc.z, s.xc.w, rp.x);
    float4 m;
    if ((unsigned)(ri - 1) < (unsigned)IMG_H) {
        m.x = min3f(s.hm1.x, s.hm2.x, h.x);
        m.y = min3f(s.hm1.y, s.hm2.y, h.y);
        m.z = min3f(s.hm1.z, s.hm2.z, h.z);
        m.w = min3f(s.hm1.w, s.hm2.w, h.w);
    } else {
        m = f4(-INF);
    }
    float4 q;
    q.x = max3f(lp.y,   s.m2.x, s.m2.y);
    q.y = max3f(s.m2.x, s.m2.y, s.m2.z);
    q.z = max3f(s.m2.y, s.m2.z, s.m2.w);
    q.w = max3f(s.m2.z, s.m2.w, rp.y);
    float4 M;
    M.x = max3f(s.q1.x, s.q2.x, q.x);
    M.y = max3f(s.q1.y, s.q2.y, q.y);
    M.z = max3f(s.q1.z, s.q2.z, q.z);
    M.w = max3f(s.q1.w, s.q2.w, q.w);
    float4 e;
    e.x = fmaxf(s.x3.x - fmaxf(M.x - s.m3.x, 0.f), 0.f);
    e.y = fmaxf(s.x3.y - fmaxf(M.y - s.m3.y, 0.f), 0.f);
    e.z = fmaxf(s.x3.z - fmaxf(M.z - s.m3.z, 0.f), 0.f);
    e.w = fmaxf(s.x3.w - fmaxf(M.w - s.m3.w, 0.f), 0.f);
    s.hm1 = s.hm2; s.hm2 = h;
    s.m3  = s.m2;  s.m2  = m;
    s.q1  = s.q2;  s.q2  = q;
    s.x3  = s.x2;  s.x2  = s.x1; s.x1 = s.xc;
    return e;
}

template<int BUF, int FIRST, int LAST>
__device__ __forceinline__ void iter_step(
    int y, int t, int c, int r0, St (&st)[K],
    const float* __restrict__ f32src, const unsigned short* __restrict__ bsrc,
    unsigned short* __restrict__ bdst, const float* __restrict__ oth,
    float& a1, float& a2,
    float2 (&eL)[K][2][EW], float2 (&eR)[K][2][EW])
{
    const float INF = __builtin_huge_valf();
    // prefetch stage-0 input row y+1
    float4 xnext = f4(INF);
    if ((unsigned)(y + 1) < (unsigned)IMG_H) {
        if constexpr (FIRST) {
            xnext = *(const float4*)(f32src + (size_t)(y + 1) * IMG_W + c);
        } else {
            ushort4 u = *(const ushort4*)(bsrc + (size_t)(y + 1) * IMG_W + c);
            xnext = make_float4(bf2f(u.x), bf2f(u.y), bf2f(u.z), bf2f(u.w));
        }
    }
    __syncthreads();                         // prev-iter edge writes visible

    float4 eK = stage_step<BUF>(st[K - 1], y - 4 * (K - 1), t, eL[K - 1], eR[K - 1]);
    #pragma unroll
    for (int k = K - 2; k >= 0; --k) {
        float4 e = stage_step<BUF>(st[k], y - 4 * k, t, eL[k], eR[k]);
        int er = y - 4 * k - 3;              // row emitted by stage k
        st[k + 1].xc = ((unsigned)er < (unsigned)IMG_H) ? e : f4(INF);
    }
    st[0].xc = xnext;

    // edge writes for next iteration
    #pragma unroll
    for (int k = 0; k < K; ++k) {
        eL[k][BUF ^ 1][t + 1] = make_float2(st[k].xc.x, st[k].m2.x);
        eR[k][BUF ^ 1][t + 1] = make_float2(st[k].xc.w, st[k].m2.w);
    }

    int orow = y - (4 * (K - 1) + 3);        // y - 15
    if ((unsigned)(orow - r0) < (unsigned)BH) {
        if constexpr (!LAST) {
            ushort4 u;
            u.x = f2bf(eK.x); u.y = f2bf(eK.y); u.z = f2bf(eK.z); u.w = f2bf(eK.w);
            *(ushort4*)(bdst + (size_t)orow * IMG_W + c) = u;
        } else {
            float4 ov = *(const float4*)(oth + (size_t)orow * IMG_W + c);
            a1 += eK.x * ov.x + eK.y * ov.y + eK.z * ov.z + eK.w * ov.w;
            a2 += eK.x + eK.y + eK.z + eK.w;
        }
    }
}

template<int FIRST, int LAST>
__global__ __launch_bounds__(256, 2) void skel(
    const unsigned short* __restrict__ src, unsigned short* __restrict__ dst,
    const float* __restrict__ pred32, const float* __restrict__ gt32,
    double* __restrict__ partials)
{
    __shared__ float2 eL[K][2][EW];   // {x.x, m.x} per lane, slot t+1
    __shared__ float2 eR[K][2][EW];   // {x.w, m.w} per lane, slot t+1
    __shared__ double l1[4], l2[4];

    const int t = threadIdx.x, c = 4 * t;
    const int band = blockIdx.x, z = blockIdx.y;
    const int r0 = band * BH;
    const float INF = __builtin_huge_valf();

    const float* f32src = (z < NIMG) ? pred32 + (size_t)z * IMG_N
                                     : gt32 + (size_t)(z - NIMG) * IMG_N;
    const unsigned short* bsrc = FIRST ? nullptr : src + (size_t)z * IMG_N;
    unsigned short* bdst = LAST ? nullptr : dst + (size_t)z * IMG_N;
    const float* oth = LAST ? ((z < NIMG) ? gt32 + (size_t)z * IMG_N
                                          : pred32 + (size_t)(z - NIMG) * IMG_N)
                            : nullptr;

    if (t < K) {
        #pragma unroll
        for (int b = 0; b < 2; ++b) {
            eR[t][b][0]      = make_float2(INF, -INF);   // left image guard
            eL[t][b][EW - 1] = make_float2(INF, -INF);   // right image guard
        }
    }

    St st[K];
    #pragma unroll
    for (int k = 0; k < K; ++k) {
        st[k].hm1 = st[k].hm2 = f4(INF);
        st[k].m2 = st[k].m3 = f4(-INF);
        st[k].q1 = st[k].q2 = f4(-INF);
        st[k].x1 = st[k].x2 = st[k].x3 = f4(INF);
        st[k].xc = f4(INF);
    }

    const int y0 = r0 - 2 * K;
    if ((unsigned)y0 < (unsigned)IMG_H) {
        if constexpr (FIRST) {
            st[0].xc = *(const float4*)(f32src + (size_t)y0 * IMG_W + c);
        } else {
            ushort4 u = *(const ushort4*)(bsrc + (size_t)y0 * IMG_W + c);
            st[0].xc = make_float4(bf2f(u.x), bf2f(u.y), bf2f(u.z), bf2f(u.w));
        }
    }

    // prologue edge write into buf 0 (consumed by first iteration)
    #pragma unroll
    for (int k = 0; k < K; ++k) {
        eL[k][0][t + 1] = make_float2(st[k].xc.x, st[k].m2.x);
        eR[k][0][t + 1] = make_float2(st[k].xc.w, st[k].m2.w);
    }

    float a1 = 0.f, a2 = 0.f;
    for (int p = 0; p < ITER_PAIRS; ++p) {
        int y = y0 + 2 * p;
        iter_step<0, FIRST, LAST>(y,     t, c, r0, st, f32src, bsrc, bdst, oth, a1, a2, eL, eR);
        iter_step<1, FIRST, LAST>(y + 1, t, c, r0, st, f32src, bsrc, bdst, oth, a1, a2, eL, eR);
    }

    if constexpr (LAST) {                    // per-block partials (no atomics)
        double d1 = a1, d2 = a2;
        for (int off = 32; off; off >>= 1) {
            d1 += __shfl_down(d1, off);
            d2 += __shfl_down(d2, off);
        }
        const int w = t >> 6;
        if ((t & 63) == 0) { l1[w] = d1; l2[w] = d2; }
        __syncthreads();
        if (t == 0) {
            int bid = z * NBANDS + band;
            partials[2 * bid]     = l1[0] + l1[1] + l1[2] + l1[3];
            partials[2 * bid + 1] = l2[0] + l2[1] + l2[2] + l2[3];
        }
    }
}

__global__ __launch_bounds__(256) void finalize(
    const double* __restrict__ pp, float* __restrict__ out)
{
    __shared__ double sh[4][4];
    double i1 = 0, i2 = 0, t1 = 0, t2 = 0;
    for (int i = threadIdx.x; i < NBLK; i += 256) {
        double a = pp[2 * i], b = pp[2 * i + 1];
        if (i < NIMG * NBANDS) { i1 += a; i2 += b; }   // z < 16: cl_pred side
        else                   { t1 += a; t2 += b; }   // z >= 16: skel_gt side
    }
    for (int off = 32; off; off >>= 1) {
        i1 += __shfl_down(i1, off); i2 += __shfl_down(i2, off);
        t1 += __shfl_down(t1, off); t2 += __shfl_down(t2, off);
    }
    const int w = threadIdx.x >> 6;
    if ((threadIdx.x & 63) == 0) { sh[0][w] = i1; sh[1][w] = i2; sh[2][w] = t1; sh[3][w] = t2; }
    __syncthreads();
    if (threadIdx.x == 0) {
        double s1 = 0, s2 = 0, s3 = 0, s4 = 0;
        for (int j = 0; j < 4; ++j) { s1 += sh[0][j]; s2 += sh[1][j]; s3 += sh[2][j]; s4 += sh[3][j]; }
        double iflat = (s1 + 1.0) / (s2 + 1.0);
        double tflat = (s3 + 1.0) / (s4 + 1.0);
        out[0] = (float)(1.0 - 2.0 * (iflat * tflat) / (iflat + tflat));
    }
}

extern "C" void kernel_launch(void* const* d_in, const int* in_sizes, int n_in,
                              void* d_out, int out_size, void* d_ws, size_t ws_size,
                              hipStream_t stream)
{
    const float* pred = (const float*)d_in[0];
    const float* gt   = (const float*)d_in[1];

    unsigned short* A = (unsigned short*)d_ws;            // 32 bf16 images (67,108,864 B)
    unsigned short* B = A + (size_t)NZ * IMG_N;           // 32 bf16 images
    double* partials  = (double*)d_ws;                    // overlaps A; A is dead
                                                          // when launch 5 (reads B) runs
    dim3 grid(NBANDS, NZ);                                // 32 bands x 32 images = 1024 blocks

    skel<1, 0><<<grid, 256, 0, stream>>>(nullptr, A, pred, gt, nullptr);  // iters 1-4
    skel<0, 0><<<grid, 256, 0, stream>>>(A, B, pred, gt, nullptr);        // 5-8
    skel<0, 0><<<grid, 256, 0, stream>>>(B, A, pred, gt, nullptr);        // 9-12
    skel<0, 0><<<grid, 256, 0, stream>>>(A, B, pred, gt, nullptr);        // 13-16
    skel<0, 1><<<grid, 256, 0, stream>>>(B, nullptr, pred, gt, partials); // 17-20 + sums

    finalize<<<1, 256, 0, stream>>>(partials, (float*)d_out);
}

// Round 10
// 644.006 us; speedup vs baseline: 1.5669x; 1.1575x over previous
//
#include <hip/hip_runtime.h>
#include <math.h>

// clDice loss on MI355X (gfx950).
// soft_skeletonize = 20 iterations of:
//   m = minpool3(x); contour = relu(maxpool3(m) - m); x = relu(x - contour)
// Round-10: packed-f16 pipeline. Round-9 was VALU-issue-bound (mid-launches
// fully L3-resident, FETCH~0, same 155 us as traffic-heavy launches; issue
// arithmetic matched wall at 59% VALUBusy) with occupancy VGPR-capped at
// 4 waves/SIMD. So: halve the instruction stream with v_pk_min/max_f16.
// All state/compute in _Float16x2 vectors (values in [0,1]; 16-bit
// intermediates already proven at absmax 0.0 with bf16 - f16 has 3 more
// mantissa bits). Structure unchanged from passing round-9: K=4 fused
// iterations/launch, both tensors per grid (z=32, 1024 blocks), LDS edge
// exchange (now one uint2 {left-pair,right-pair} per stage), 1 barrier per
// row-iter, per-block partials, 5 launches + finalize.

#define IMG_H 1024
#define IMG_W 1024
#define IMG_N (IMG_H * IMG_W)
#define NIMG  16
#define NZ    32                    // 16 pred + 16 gt images
#define BH    32                    // output rows per band
#define NBANDS (IMG_H / BH)         // 32
#define K     4                     // fused skeleton iterations per launch
#define EW    258                   // 256 lanes + 2 guard slots
#define NBLK  (NZ * NBANDS)         // 1024 blocks per launch
#define ITER_PAIRS ((BH + 6 * K) / 2)   // 28 pairs = 56 row-iterations

typedef _Float16 h2 __attribute__((ext_vector_type(2)));

__device__ __forceinline__ h2 hmin2(h2 a, h2 b) { return __builtin_elementwise_min(a, b); }
__device__ __forceinline__ h2 hmax2(h2 a, h2 b) { return __builtin_elementwise_max(a, b); }

union U32H { unsigned u; h2 h; };
__device__ __forceinline__ unsigned as_u(h2 h) { U32H t; t.h = h; return t.u; }
__device__ __forceinline__ h2 as_h2(unsigned u) { U32H t; t.u = u; return t.h; }

struct Hp { h2 lo, hi; };           // 4 image columns per lane
struct St { Hp hm1, hm2, m2, m3, q1, q2, x1, x2, x3, xc; };

// One pipeline stage. rmask: +inf pass / -inf force (maxpool row padding).
// Edge pair layout: e2[slot].x = {x_col0, m_col0} (read by LEFT-seeking
// neighbor at slot t+2); e2[slot].y = {x_col3, m_col3} (read at slot t).
template<int BUF>
__device__ __forceinline__ Hp stage_step(
    St& s, h2 rmask, int t, const uint2 (&e2)[2][EW])
{
    h2 lp = as_h2(e2[BUF][t].y);        // left nbr's col3 {x, m}
    h2 rp = as_h2(e2[BUF][t + 2].x);    // right nbr's col0 {x, m}
    // h-min3 of x row
    h2 midx = (h2){s.xc.lo[1], s.xc.hi[0]};               // {x1, x2}
    h2 hlo = hmin2(hmin2((h2){lp[0], s.xc.lo[0]}, s.xc.lo), midx);
    h2 hhi = hmin2(hmin2(midx, s.xc.hi), (h2){s.xc.hi[1], rp[0]});
    // v-min3 + row-validity mask
    h2 mlo = hmin2(hmin2(hmin2(s.hm1.lo, s.hm2.lo), hlo), rmask);
    h2 mhi = hmin2(hmin2(hmin2(s.hm1.hi, s.hm2.hi), hhi), rmask);
    // h-max3 of m (previous iter's m, in m2; neighbor edges from LDS)
    h2 midm = (h2){s.m2.lo[1], s.m2.hi[0]};
    h2 qlo = hmax2(hmax2((h2){lp[1], s.m2.lo[0]}, s.m2.lo), midm);
    h2 qhi = hmax2(hmax2(midm, s.m2.hi), (h2){s.m2.hi[1], rp[1]});
    // v-max3
    h2 Mlo = hmax2(hmax2(s.q1.lo, s.q2.lo), qlo);
    h2 Mhi = hmax2(hmax2(s.q1.hi, s.q2.hi), qhi);
    // contour + relu update
    const h2 Z2 = (h2){(_Float16)0.f, (_Float16)0.f};
    h2 elo = hmax2(s.x3.lo - hmax2(Mlo - s.m3.lo, Z2), Z2);
    h2 ehi = hmax2(s.x3.hi - hmax2(Mhi - s.m3.hi, Z2), Z2);
    // ring shifts
    s.hm1 = s.hm2; s.hm2.lo = hlo; s.hm2.hi = hhi;
    s.m3  = s.m2;  s.m2.lo  = mlo; s.m2.hi  = mhi;
    s.q1  = s.q2;  s.q2.lo  = qlo; s.q2.hi  = qhi;
    s.x3  = s.x2;  s.x2 = s.x1;    s.x1 = s.xc;
    Hp e; e.lo = elo; e.hi = ehi;
    return e;
}

template<int BUF, int FIRST, int LAST>
__device__ __forceinline__ void iter_step(
    int y, int t, int c, int r0, St (&st)[K],
    const float* __restrict__ f32src, const unsigned short* __restrict__ bsrc,
    unsigned short* __restrict__ bdst, const float* __restrict__ oth,
    float& a1, float& a2, uint2 (&e2)[K][2][EW])
{
    const _Float16 HINF = (_Float16)__builtin_huge_valf();
    const h2 PINF2 = (h2){HINF, HINF};
    const h2 NINF2 = (h2){-HINF, -HINF};

    // prefetch stage-0 input row y+1
    Hp xnext; xnext.lo = PINF2; xnext.hi = PINF2;
    if ((unsigned)(y + 1) < (unsigned)IMG_H) {
        if constexpr (FIRST) {
            float4 f = *(const float4*)(f32src + (size_t)(y + 1) * IMG_W + c);
            xnext.lo = (h2){(_Float16)f.x, (_Float16)f.y};
            xnext.hi = (h2){(_Float16)f.z, (_Float16)f.w};
        } else {
            uint2 u = *(const uint2*)(bsrc + (size_t)(y + 1) * IMG_W + c);
            xnext.lo = as_h2(u.x);
            xnext.hi = as_h2(u.y);
        }
    }
    __syncthreads();                         // prev-iter edge writes visible

    h2 rm = ((unsigned)(y - 13) < (unsigned)IMG_H) ? PINF2 : NINF2;
    Hp eK = stage_step<BUF>(st[K - 1], rm, t, e2[K - 1]);
    #pragma unroll
    for (int k = K - 2; k >= 0; --k) {
        rm = ((unsigned)(y - 4 * k - 1) < (unsigned)IMG_H) ? PINF2 : NINF2;
        Hp e = stage_step<BUF>(st[k], rm, t, e2[k]);
        h2 em = ((unsigned)(y - 4 * k - 3) < (unsigned)IMG_H) ? NINF2 : PINF2;
        st[k + 1].xc.lo = hmax2(e.lo, em);   // max(e,-inf)=e; max(e,+inf)=+inf
        st[k + 1].xc.hi = hmax2(e.hi, em);
    }
    st[0].xc = xnext;

    // edge writes for next iteration (new xc + this iter's m, now in m2)
    #pragma unroll
    for (int k = 0; k < K; ++k) {
        e2[k][BUF ^ 1][t + 1] = make_uint2(
            as_u((h2){st[k].xc.lo[0], st[k].m2.lo[0]}),
            as_u((h2){st[k].xc.hi[1], st[k].m2.hi[1]}));
    }

    int orow = y - (4 * (K - 1) + 3);        // y - 15
    if ((unsigned)(orow - r0) < (unsigned)BH) {
        if constexpr (!LAST) {
            *(uint2*)(bdst + (size_t)orow * IMG_W + c) =
                make_uint2(as_u(eK.lo), as_u(eK.hi));
        } else {
            float4 ov = *(const float4*)(oth + (size_t)orow * IMG_W + c);
            float e0 = (float)eK.lo[0], e1 = (float)eK.lo[1];
            float e2f = (float)eK.hi[0], e3 = (float)eK.hi[1];
            a1 += e0 * ov.x + e1 * ov.y + e2f * ov.z + e3 * ov.w;
            a2 += e0 + e1 + e2f + e3;
        }
    }
}

template<int FIRST, int LAST>
__global__ __launch_bounds__(256, 2) void skel(
    const unsigned short* __restrict__ src, unsigned short* __restrict__ dst,
    const float* __restrict__ pred32, const float* __restrict__ gt32,
    double* __restrict__ partials)
{
    __shared__ uint2 e2[K][2][EW];    // {.x = col0 pair, .y = col3 pair}
    __shared__ double l1[4], l2[4];

    const int t = threadIdx.x, c = 4 * t;
    const int band = blockIdx.x, z = blockIdx.y;
    const int r0 = band * BH;
    const _Float16 HINF = (_Float16)__builtin_huge_valf();
    const h2 PINF2 = (h2){HINF, HINF};
    const h2 NINF2 = (h2){-HINF, -HINF};

    const float* f32src = (z < NIMG) ? pred32 + (size_t)z * IMG_N
                                     : gt32 + (size_t)(z - NIMG) * IMG_N;
    const unsigned short* bsrc = FIRST ? nullptr : src + (size_t)z * IMG_N;
    unsigned short* bdst = LAST ? nullptr : dst + (size_t)z * IMG_N;
    const float* oth = LAST ? ((z < NIMG) ? gt32 + (size_t)z * IMG_N
                                          : pred32 + (size_t)(z - NIMG) * IMG_N)
                            : nullptr;

    if (t < K) {
        #pragma unroll
        for (int b = 0; b < 2; ++b) {
            // guard pairs: x=+inf (0x7C00 low), m=-inf (0xFC00 high)
            e2[t][b][0]      = make_uint2(0u, 0xFC007C00u);  // only .y read
            e2[t][b][EW - 1] = make_uint2(0xFC007C00u, 0u);  // only .x read
        }
    }

    St st[K];
    #pragma unroll
    for (int k = 0; k < K; ++k) {
        st[k].hm1.lo = st[k].hm1.hi = PINF2;
        st[k].hm2.lo = st[k].hm2.hi = PINF2;
        st[k].m2.lo  = st[k].m2.hi  = NINF2;
        st[k].m3.lo  = st[k].m3.hi  = NINF2;
        st[k].q1.lo  = st[k].q1.hi  = NINF2;
        st[k].q2.lo  = st[k].q2.hi  = NINF2;
        st[k].x1.lo  = st[k].x1.hi  = PINF2;
        st[k].x2.lo  = st[k].x2.hi  = PINF2;
        st[k].x3.lo  = st[k].x3.hi  = PINF2;
        st[k].xc.lo  = st[k].xc.hi  = PINF2;
    }

    const int y0 = r0 - 2 * K;
    if ((unsigned)y0 < (unsigned)IMG_H) {
        if constexpr (FIRST) {
            float4 f = *(const float4*)(f32src + (size_t)y0 * IMG_W + c);
            st[0].xc.lo = (h2){(_Float16)f.x, (_Float16)f.y};
            st[0].xc.hi = (h2){(_Float16)f.z, (_Float16)f.w};
        } else {
            uint2 u = *(const uint2*)(bsrc + (size_t)y0 * IMG_W + c);
            st[0].xc.lo = as_h2(u.x);
            st[0].xc.hi = as_h2(u.y);
        }
    }

    // prologue edge write into buf 0 (consumed by first iteration)
    #pragma unroll
    for (int k = 0; k < K; ++k) {
        e2[k][0][t + 1] = make_uint2(
            as_u((h2){st[k].xc.lo[0], st[k].m2.lo[0]}),
            as_u((h2){st[k].xc.hi[1], st[k].m2.hi[1]}));
    }

    float a1 = 0.f, a2 = 0.f;
    for (int p = 0; p < ITER_PAIRS; ++p) {
        int y = y0 + 2 * p;
        iter_step<0, FIRST, LAST>(y,     t, c, r0, st, f32src, bsrc, bdst, oth, a1, a2, e2);
        iter_step<1, FIRST, LAST>(y + 1, t, c, r0, st, f32src, bsrc, bdst, oth, a1, a2, e2);
    }

    if constexpr (LAST) {                    // per-block partials (no atomics)
        double d1 = a1, d2 = a2;
        for (int off = 32; off; off >>= 1) {
            d1 += __shfl_down(d1, off);
            d2 += __shfl_down(d2, off);
        }
        const int w = t >> 6;
        if ((t & 63) == 0) { l1[w] = d1; l2[w] = d2; }
        __syncthreads();
        if (t == 0) {
            int bid = z * NBANDS + band;
            partials[2 * bid]     = l1[0] + l1[1] + l1[2] + l1[3];
            partials[2 * bid + 1] = l2[0] + l2[1] + l2[2] + l2[3];
        }
    }
}

__global__ __launch_bounds__(256) void finalize(
    const double* __restrict__ pp, float* __restrict__ out)
{
    __shared__ double sh[4][4];
    double i1 = 0, i2 = 0, t1 = 0, t2 = 0;
    for (int i = threadIdx.x; i < NBLK; i += 256) {
        double a = pp[2 * i], b = pp[2 * i + 1];
        if (i < NIMG * NBANDS) { i1 += a; i2 += b; }   // z < 16: cl_pred side
        else                   { t1 += a; t2 += b; }   // z >= 16: skel_gt side
    }
    for (int off = 32; off; off >>= 1) {
        i1 += __shfl_down(i1, off); i2 += __shfl_down(i2, off);
        t1 += __shfl_down(t1, off); t2 += __shfl_down(t2, off);
    }
    const int w = threadIdx.x >> 6;
    if ((threadIdx.x & 63) == 0) { sh[0][w] = i1; sh[1][w] = i2; sh[2][w] = t1; sh[3][w] = t2; }
    __syncthreads();
    if (threadIdx.x == 0) {
        double s1 = 0, s2 = 0, s3 = 0, s4 = 0;
        for (int j = 0; j < 4; ++j) { s1 += sh[0][j]; s2 += sh[1][j]; s3 += sh[2][j]; s4 += sh[3][j]; }
        double iflat = (s1 + 1.0) / (s2 + 1.0);
        double tflat = (s3 + 1.0) / (s4 + 1.0);
        out[0] = (float)(1.0 - 2.0 * (iflat * tflat) / (iflat + tflat));
    }
}

extern "C" void kernel_launch(void* const* d_in, const int* in_sizes, int n_in,
                              void* d_out, int out_size, void* d_ws, size_t ws_size,
                              hipStream_t stream)
{
    const float* pred = (const float*)d_in[0];
    const float* gt   = (const float*)d_in[1];

    unsigned short* A = (unsigned short*)d_ws;            // 32 f16 images (64 MiB)
    unsigned short* B = A + (size_t)NZ * IMG_N;           // 32 f16 images
    double* partials  = (double*)d_ws;                    // overlaps A; A is dead
                                                          // when launch 5 (reads B) runs
    dim3 grid(NBANDS, NZ);                                // 32 bands x 32 images

    skel<1, 0><<<grid, 256, 0, stream>>>(nullptr, A, pred, gt, nullptr);  // iters 1-4
    skel<0, 0><<<grid, 256, 0, stream>>>(A, B, pred, gt, nullptr);        // 5-8
    skel<0, 0><<<grid, 256, 0, stream>>>(B, A, pred, gt, nullptr);        // 9-12
    skel<0, 0><<<grid, 256, 0, stream>>>(A, B, pred, gt, nullptr);        // 13-16
    skel<0, 1><<<grid, 256, 0, stream>>>(B, nullptr, pred, gt, partials); // 17-20 + sums

    finalize<<<1, 256, 0, stream>>>(partials, (float*)d_out);
}